// Round 5
// baseline (5991.352 us; speedup 1.0000x reference)
//
#include <hip/hip_runtime.h>
#include <hip/hip_bf16.h>

// ---------------------------------------------------------------------------
// LSTM (B=128, T=512, I=H=1024) + final FC (O=256) on gfx950.
// prep -> xcast -> gemm_xg (bf16, time-major, gate-interleaved cols) ->
// lstm_rec v5 -> fc_out.
//
// lstm_rec v5: 256 persistent blocks = 4 m-quarters x 64 n-blocks.
// Block = 32 batch rows x 16 h-cols; wave = 4 h-cols (16 gate rows), K=1024.
// w_hh slice per wave = 128 VGPRs (breg[32] v8bf) -- small enough to stay
// register-resident (R4's 256-VGPR version sank to per-step L2 reloads,
// VGPR_Count=160 proved it). h exchanged as tagged granules
// {h0,h1,tag=t} via relaxed agent(sc1) 8B atomic stores/loads.
// Phase 1 issues ALL 64 tagged loads per wave before checking (R4 serialized
// 8 poll round-trips, ~7200cy/step -- the dominant cost).
// One __syncthreads per step; no fences; no atomic RMW.
// Tag protocol also orders hA reuse: a block's poll includes its own waves'
// granules, which are stored only after those waves' hA reads completed ->
// single hA buffer is safe.
// Gate permutation: permuted row n = ns*64 + w*16 + g*4 + jl,
//   hcol = ns*16 + w*4 + jl, orig row = g*1024 + hcol.
// xg layout: out col = hcol*4 + g  (one u64 granule = 4 gates of one hcol).
// ---------------------------------------------------------------------------

typedef float  v4f  __attribute__((ext_vector_type(4)));
typedef __bf16 v8bf __attribute__((ext_vector_type(8)));
typedef __bf16 v4bf __attribute__((ext_vector_type(4)));

#define NBLK_REC 256

// ---------------- workspace layout (bytes) ----------------
static constexpr size_t XG_B    = (size_t)512 * 128 * 4096 * 2;      // 512 MiB
static constexpr size_t WIHP_O  = XG_B;
static constexpr size_t WHHP_O  = WIHP_O + (size_t)4096 * 1024 * 2;
static constexpr size_t BIASP_O = WHHP_O + (size_t)4096 * 1024 * 2;
static constexpr size_t HBUF_O  = BIASP_O + 16384;                   // 2*512KiB u64 granules
static constexpr size_t XB_O    = HBUF_O + (size_t)2 * 128 * 512 * 8;
static constexpr size_t WS_FULL = XB_O + (size_t)128 * 512 * 1024 * 2;

__device__ __forceinline__ float bf2f(unsigned short u) {
    union { unsigned u32; float f; } c; c.u32 = (unsigned)u << 16; return c.f;
}

// ---------------------------------------------------------------------------
// prep: permute+convert weights, tagged h0 granules, scrub parity-1 tags
// hcol(n) = (n>>6)*16 + ((n>>4)&3)*4 + (n&3); g(n) = (n>>2)&3
// ---------------------------------------------------------------------------
__global__ __launch_bounds__(256) void prep_kernel(
    const float* __restrict__ w_ih, const float* __restrict__ w_hh,
    const float* __restrict__ bias, const float* __restrict__ h0,
    __bf16* __restrict__ w_ihp, __bf16* __restrict__ w_hhp,
    float* __restrict__ biasp, unsigned long long* __restrict__ hb)
{
    const int idx = blockIdx.x * 256 + threadIdx.x;       // 0 .. 4194303
    const int n = idx >> 10, k = idx & 1023;
    const int hcol = (n >> 6) * 16 + ((n >> 4) & 3) * 4 + (n & 3);
    const int g = (n >> 2) & 3;
    const int on = g * 1024 + hcol;
    w_ihp[idx] = (__bf16)w_ih[(size_t)on * 1024 + k];
    w_hhp[idx] = (__bf16)w_hh[(size_t)on * 1024 + k];
    if (idx < 4096) {
        const int hc2 = (idx >> 6) * 16 + ((idx >> 4) & 3) * 4 + (idx & 3);
        biasp[idx] = bias[((idx >> 2) & 3) * 1024 + hc2];
    }
    if (idx < 128 * 512) {   // tagged h0 granules, tag=0 (parity-0 buffer)
        const int m = idx >> 9, jp = idx & 511;
        union { __bf16 b; unsigned short u; } c0h, c1h;
        c0h.b = (__bf16)h0[(size_t)m * 1024 + jp * 2];
        c1h.b = (__bf16)h0[(size_t)m * 1024 + jp * 2 + 1];
        hb[idx] = (unsigned long long)c0h.u | ((unsigned long long)c1h.u << 16);
        hb[65536 + idx] = 0xFFFFull << 32;   // parity-1: never-matching tag
    }
}

// ---------------------------------------------------------------------------
__global__ __launch_bounds__(256) void xcast(
    const float* __restrict__ x, __bf16* __restrict__ xb)
{
    const size_t i = ((size_t)blockIdx.x * 256 + threadIdx.x) * 8;
    const float4 a = *(const float4*)&x[i];
    const float4 b = *(const float4*)&x[i + 4];
    v8bf o = { (__bf16)a.x, (__bf16)a.y, (__bf16)a.z, (__bf16)a.w,
               (__bf16)b.x, (__bf16)b.y, (__bf16)b.z, (__bf16)b.w };
    *(v8bf*)&xb[i] = o;
}

// ---------------------------------------------------------------------------
// gemm_xg (bf16): tile 128x128, 4 waves 2x2, BK=64, LDS epilogue.
// col remap within tile: outl = (nl>>6)*64 + ((nl>>4)&3)*16 + (nl&3)*4 + ((nl>>2)&3)
// ---------------------------------------------------------------------------
__global__ __launch_bounds__(256) void gemm_xg_bf16(
    const __bf16* __restrict__ xb, const __bf16* __restrict__ wih,
    const float* __restrict__ biasp, __bf16* __restrict__ xg)
{
    const int bx = blockIdx.x;
    const int mtile = bx >> 5, ntile = bx & 31;
    const int m0 = mtile << 7, n0 = ntile << 7;
    const int bb = mtile >> 2, t0 = (mtile & 3) << 7;
    const int tid = threadIdx.x;
    const int lane = tid & 63, wave = tid >> 6;
    const int wm = wave >> 1, wn = wave & 1;
    const int l15 = lane & 15, q = lane >> 4;

    __shared__ union {
        struct { __bf16 A[128][72]; __bf16 B[128][72]; } s;
        __bf16 C[128][132];
    } u;

    const int sr = tid >> 3, sc = (tid & 7) * 8;
    const __bf16* ag = xb  + (size_t)(m0 + sr) * 1024 + sc;
    const __bf16* bg = wih + (size_t)(n0 + sr) * 1024 + sc;

    v4f acc[4][4] = {};
    for (int kt = 0; kt < 16; ++kt) {
        __syncthreads();
        #pragma unroll
        for (int i = 0; i < 4; ++i) {
            *(v8bf*)&u.s.A[sr + i * 32][sc] = *(const v8bf*)(ag + (size_t)i * 32 * 1024 + kt * 64);
            *(v8bf*)&u.s.B[sr + i * 32][sc] = *(const v8bf*)(bg + (size_t)i * 32 * 1024 + kt * 64);
        }
        __syncthreads();
        v8bf a[2][4], b[2][4];
        #pragma unroll
        for (int ks = 0; ks < 2; ++ks) {
            #pragma unroll
            for (int im = 0; im < 4; ++im)
                a[ks][im] = *(const v8bf*)&u.s.A[wm * 64 + im * 16 + l15][ks * 32 + q * 8];
            #pragma unroll
            for (int in_ = 0; in_ < 4; ++in_)
                b[ks][in_] = *(const v8bf*)&u.s.B[wn * 64 + in_ * 16 + l15][ks * 32 + q * 8];
        }
        #pragma unroll
        for (int ks = 0; ks < 2; ++ks)
            #pragma unroll
            for (int im = 0; im < 4; ++im)
                #pragma unroll
                for (int in_ = 0; in_ < 4; ++in_)
                    acc[im][in_] = __builtin_amdgcn_mfma_f32_16x16x32_bf16(
                        a[ks][im], b[ks][in_], acc[im][in_], 0, 0, 0);
    }
    __syncthreads();
    #pragma unroll
    for (int in_ = 0; in_ < 4; ++in_) {
        const int nl = wn * 64 + in_ * 16 + l15;
        const int outl = ((nl >> 6) << 6) | ((((nl >> 4) & 3)) << 4)
                       | ((nl & 3) << 2) | ((nl >> 2) & 3);
        const float bv = biasp[n0 + nl];
        #pragma unroll
        for (int im = 0; im < 4; ++im)
            #pragma unroll
            for (int r = 0; r < 4; ++r)
                u.C[wm * 64 + im * 16 + q * 4 + r][outl] = (__bf16)(acc[im][in_][r] + bv);
    }
    __syncthreads();
    const int cr = tid >> 1, chf = (tid & 1) * 64;
    __bf16* outp = xg + ((size_t)(t0 + cr) * 128 + bb) * 4096 + n0 + chf;
    #pragma unroll
    for (int j = 0; j < 8; ++j)
        *(uint4*)(outp + j * 8) = *(const uint4*)&u.C[cr][chf + j * 8];
}

// fallback: fp32 A staging (used only if ws too small for xb)
__global__ __launch_bounds__(256) void gemm_xg_f32(
    const float* __restrict__ x, const __bf16* __restrict__ wih,
    const float* __restrict__ biasp, __bf16* __restrict__ xg)
{
    const int bx = blockIdx.x;
    const int mtile = bx >> 5, ntile = bx & 31;
    const int m0 = mtile << 7, n0 = ntile << 7;
    const int bb = mtile >> 2, t0 = (mtile & 3) << 7;
    const int tid = threadIdx.x;
    const int lane = tid & 63, wave = tid >> 6;
    const int wm = wave >> 1, wn = wave & 1;
    const int l15 = lane & 15, q = lane >> 4;

    __shared__ __bf16 Al[128][40];
    __shared__ __bf16 Bl[128][40];
    v4f acc[4][4] = {};

    for (int kt = 0; kt < 32; ++kt) {
        __syncthreads();
        const int k0 = kt * 32;
        #pragma unroll
        for (int i = 0; i < 4; ++i) {
            const int s = tid + i * 256, r = s >> 3, c = s & 7;
            const float4 v = *(const float4*)&x[(size_t)(m0 + r) * 1024 + k0 + c * 4];
            v4bf pk = { (__bf16)v.x, (__bf16)v.y, (__bf16)v.z, (__bf16)v.w };
            *(v4bf*)&Al[r][c * 4] = pk;
        }
        #pragma unroll
        for (int j = 0; j < 2; ++j) {
            const int s = tid + j * 256, r = s >> 2, ch = s & 3;
            const uint4 v = *(const uint4*)&wih[(size_t)(n0 + r) * 1024 + k0 + ch * 8];
            *(uint4*)&Bl[r][ch * 8] = v;
        }
        __syncthreads();
        v8bf a[4], b[4];
        #pragma unroll
        for (int im = 0; im < 4; ++im) a[im] = *(const v8bf*)&Al[wm * 64 + im * 16 + l15][q * 8];
        #pragma unroll
        for (int in_ = 0; in_ < 4; ++in_) b[in_] = *(const v8bf*)&Bl[wn * 64 + in_ * 16 + l15][q * 8];
        #pragma unroll
        for (int im = 0; im < 4; ++im)
            #pragma unroll
            for (int in_ = 0; in_ < 4; ++in_)
                acc[im][in_] = __builtin_amdgcn_mfma_f32_16x16x32_bf16(a[im], b[in_], acc[im][in_], 0, 0, 0);
    }
    #pragma unroll
    for (int in_ = 0; in_ < 4; ++in_) {
        const int nl = wn * 64 + in_ * 16 + l15;
        const int outl = ((nl >> 6) << 6) | ((((nl >> 4) & 3)) << 4)
                       | ((nl & 3) << 2) | ((nl >> 2) & 3);
        const float bv = biasp[n0 + nl];
        #pragma unroll
        for (int im = 0; im < 4; ++im) {
            const int mbase = wm * 64 + im * 16 + q * 4;
            #pragma unroll
            for (int r = 0; r < 4; ++r)
                xg[((size_t)(t0 + mbase + r) * 128 + bb) * 4096 + n0 + outl] =
                    (__bf16)(acc[im][in_][r] + bv);
        }
    }
}

// ---------------------------------------------------------------------------
// lstm_rec v5
// ---------------------------------------------------------------------------
__device__ __forceinline__ float sigm_f(float x) {
    return __builtin_amdgcn_rcpf(1.f + __expf(-x));
}
__device__ __forceinline__ float tanh_f(float x) {
    return 1.f - 2.f * __builtin_amdgcn_rcpf(__expf(2.f * x) + 1.f);
}

__global__ __launch_bounds__(256, 1) void lstm_rec(
    const __bf16* __restrict__ whh, const __bf16* __restrict__ xg,
    const float* __restrict__ c0, unsigned long long* hbuf)
{
    const int tid  = threadIdx.x;
    const int lane = tid & 63, w = tid >> 6;
    const int l15  = lane & 15, q = lane >> 4;
    const int mq   = blockIdx.x >> 6;   // quarter (32 batch rows)
    const int ns   = blockIdx.x & 63;   // n-block (16 h-cols)

    __shared__ __bf16 hA[32][1032];     // staged h(t-1), 66 KiB (single buffer)
    __shared__ float  glds[4][32][21];  // wave-private gate exchange, 10.5 KiB

    // ---- w_hh slice -> VGPRs: wave w covers 16 gate rows, 128 VGPRs ----
    v8bf breg[32];
    {
        const __bf16* wb = whh + (size_t)(ns * 64 + w * 16) * 1024;
        #pragma unroll
        for (int kc = 0; kc < 32; ++kc)
            breg[kc] = *(const v8bf*)&wb[(size_t)l15 * 1024 + kc * 32 + q * 8];
    }

    // epilogue identity: lane -> (batch row em, hcol pair jp)
    const int em = lane & 31;
    const int jp = lane >> 5;
    const int hcolG = ns * 16 + w * 4 + jp * 2;
    const int mG = mq * 32 + em;
    float2 cv = *(const float2*)&c0[(size_t)mG * 1024 + hcolG];

    #pragma unroll 1
    for (int t = 1; t <= 512; ++t) {
        const int par  = (t - 1) & 1;
        const unsigned short want = (unsigned short)(t - 1);

        // ---- xg prefetch: 2 granules (4 gates each) for (mG, hcolG/ +1) ----
        const unsigned long long* xp = (const unsigned long long*)xg
            + ((size_t)(t - 1) * 128 + mG) * 1024 + hcolG;
        const unsigned long long xq0 = xp[0];
        const unsigned long long xq1 = xp[1];

        // ---- phase 1: issue ALL 64 tagged loads, then check/retry per row ----
        const unsigned long long* hq = hbuf + (size_t)par * 65536
                                     + ((size_t)mq * 32 + w * 8) * 512;
        unsigned long long gv[8][8];
        #pragma unroll
        for (int r = 0; r < 8; ++r)
            #pragma unroll
            for (int c = 0; c < 8; ++c)
                gv[r][c] = __hip_atomic_load(hq + (size_t)r * 512 + c * 64 + lane,
                                             __ATOMIC_RELAXED, __HIP_MEMORY_SCOPE_AGENT);
        #pragma unroll
        for (int r = 0; r < 8; ++r) {
            for (;;) {
                bool ok = true;
                #pragma unroll
                for (int c = 0; c < 8; ++c)
                    ok &= ((unsigned short)(gv[r][c] >> 32) == want);
                if (__builtin_expect(__ballot(ok) == ~0ull, 1)) break;
                #pragma unroll
                for (int c = 0; c < 8; ++c)
                    gv[r][c] = __hip_atomic_load(hq + (size_t)r * 512 + c * 64 + lane,
                                                 __ATOMIC_RELAXED, __HIP_MEMORY_SCOPE_AGENT);
            }
            #pragma unroll
            for (int c = 0; c < 8; ++c)
                *(unsigned*)&hA[w * 8 + r][(c * 64 + lane) * 2] = (unsigned)gv[r][c];
        }
        __syncthreads();   // the ONLY barrier per step

        // ---- phase 2: MFMA (A rows from LDS, B resident in VGPRs) ----
        v4f acc0 = {}, acc1 = {};
        #pragma unroll
        for (int kc = 0; kc < 32; ++kc) {
            const v8bf a0 = *(const v8bf*)&hA[l15][kc * 32 + q * 8];
            const v8bf a1 = *(const v8bf*)&hA[l15 + 16][kc * 32 + q * 8];
            acc0 = __builtin_amdgcn_mfma_f32_16x16x32_bf16(a0, breg[kc], acc0, 0, 0, 0);
            acc1 = __builtin_amdgcn_mfma_f32_16x16x32_bf16(a1, breg[kc], acc1, 0, 0, 0);
        }

        // ---- phase 3: wave-private gate exchange + cell + tagged h store ----
        #pragma unroll
        for (int r = 0; r < 4; ++r) {
            glds[w][q * 4 + r][l15]      = acc0[r];
            glds[w][16 + q * 4 + r][l15] = acc1[r];
        }
        // wave-private LDS: compiler's lgkmcnt ordering suffices (same wave)
        float g0[4], g1[4];
        #pragma unroll
        for (int g = 0; g < 4; ++g) {
            g0[g] = glds[w][em][g * 4 + jp * 2]
                  + bf2f((unsigned short)(xq0 >> (16 * g)));
            g1[g] = glds[w][em][g * 4 + jp * 2 + 1]
                  + bf2f((unsigned short)(xq1 >> (16 * g)));
        }
        cv.x = sigm_f(g0[1]) * cv.x + sigm_f(g0[0]) * tanh_f(g0[2]);
        cv.y = sigm_f(g1[1]) * cv.y + sigm_f(g1[0]) * tanh_f(g1[2]);
        const float hx = sigm_f(g0[3]) * tanh_f(cv.x);
        const float hy = sigm_f(g1[3]) * tanh_f(cv.y);

        union { __bf16 b[2]; unsigned u; } hp;
        hp.b[0] = (__bf16)hx; hp.b[1] = (__bf16)hy;
        const unsigned long long wrd = (unsigned long long)hp.u
                                     | ((unsigned long long)(unsigned short)t << 32);
        __hip_atomic_store(
            hbuf + (size_t)(t & 1) * 65536 + (size_t)mG * 512 + (hcolG >> 1),
            wrd, __ATOMIC_RELAXED, __HIP_MEMORY_SCOPE_AGENT);
    }
}

// ---------------------------------------------------------------------------
// fc_out: out[b][o] = h_last[b] . w_fc[o] + b_fc[o]  (h_last: parity-0 buffer)
// ---------------------------------------------------------------------------
__global__ __launch_bounds__(256) void fc_out(
    const unsigned long long* __restrict__ hb, const float* __restrict__ wfc,
    const float* __restrict__ bfc, float* __restrict__ out)
{
    const int b = blockIdx.x, o = threadIdx.x;
    __shared__ float hs[1024];
    for (int i = threadIdx.x; i < 512; i += 256) {
        const unsigned long long g = hb[(size_t)b * 512 + i];
        hs[2 * i]     = bf2f((unsigned short)g);
        hs[2 * i + 1] = bf2f((unsigned short)(g >> 16));
    }
    __syncthreads();
    const float* wr = wfc + (size_t)o * 1024;
    float s = 0.f;
    for (int k = 0; k < 1024; k += 4) {
        const float4 w = *(const float4*)&wr[k];
        s += hs[k] * w.x + hs[k + 1] * w.y + hs[k + 2] * w.z + hs[k + 3] * w.w;
    }
    out[b * 256 + o] = s + bfc[o];
}

// ---------------------------------------------------------------------------
extern "C" void kernel_launch(void* const* d_in, const int* in_sizes, int n_in,
                              void* d_out, int out_size, void* d_ws, size_t ws_size,
                              hipStream_t stream) {
    (void)in_sizes; (void)n_in; (void)out_size;
    const float* x    = (const float*)d_in[0];
    const float* h0   = (const float*)d_in[1];
    const float* c0   = (const float*)d_in[2];
    const float* w_ih = (const float*)d_in[3];
    const float* w_hh = (const float*)d_in[4];
    const float* bias = (const float*)d_in[5];
    const float* w_fc = (const float*)d_in[6];
    const float* b_fc = (const float*)d_in[7];
    float* out = (float*)d_out;

    char* ws = (char*)d_ws;
    __bf16* xg    = (__bf16*)(ws);
    __bf16* w_ihp = (__bf16*)(ws + WIHP_O);
    __bf16* w_hhp = (__bf16*)(ws + WHHP_O);
    float*  biasp = (float*)(ws + BIASP_O);
    unsigned long long* hbuf = (unsigned long long*)(ws + HBUF_O);
    __bf16* xb    = (__bf16*)(ws + XB_O);

    prep_kernel<<<16384, 256, 0, stream>>>(w_ih, w_hh, bias, h0, w_ihp, w_hhp, biasp, hbuf);
    if (ws_size >= WS_FULL) {
        xcast<<<32768, 256, 0, stream>>>(x, xb);
        gemm_xg_bf16<<<16384, 256, 0, stream>>>(xb, w_ihp, biasp, xg);
    } else {
        gemm_xg_f32<<<16384, 256, 0, stream>>>(x, w_ihp, biasp, xg);
    }
    lstm_rec<<<NBLK_REC, 256, 0, stream>>>(w_hhp, xg, c0, hbuf);
    fc_out<<<128, 256, 0, stream>>>(hbuf, w_fc, b_fc, out);
}